// Round 2
// baseline (86381.653 us; speedup 1.0000x reference)
//
#include <hip/hip_runtime.h>
#include <math.h>

// Problem dims
#define BB   64
#define TT   512
#define LL   256
#define VOC  4096
#define NBLK 256
#define NTHR 1024

__device__ __forceinline__ float sigm(float x){ return 1.0f/(1.0f+__expf(-x)); }

// Grid barrier: monotonic epochs, device-scope atomics. All NBLK blocks must be
// co-resident (guaranteed by hipLaunchCooperativeKernel).
__device__ __forceinline__ void gbar(unsigned* arrive, int blk, int tid, unsigned ep){
  __syncthreads();
  if (tid == 0){
    __threadfence();  // release all prior global writes (agent scope)
    __hip_atomic_store(&arrive[blk], ep, __ATOMIC_RELEASE, __HIP_MEMORY_SCOPE_AGENT);
  }
  int ok;
  do {
    ok = (tid < NBLK)
       ? (__hip_atomic_load(&arrive[tid], __ATOMIC_RELAXED, __HIP_MEMORY_SCOPE_AGENT) >= ep)
       : 1;
  } while (__syncthreads_count(ok) < NTHR);
  __threadfence();  // acquire: invalidate L1 so post-barrier reads see fresh data
}

// Weight-stationary cooperative recurrence.
//  Phase A: block d (0..255) owns h1-dim d (gate cols d, d+256, d+512, d+768).
//  Phase B: block d (<128) owns h2-dim d (gate cols d, d+128, d+256, d+384).
//  Phase C: block (b = blk>>2, q = blk&3) does attention T-chunk [q*128, q*128+128);
//           q==0 combines the 4 online-softmax partials (flag handshake) and writes
//           ctxbuf + states row for the final logits GEMM.
extern "C" __global__ void __launch_bounds__(NTHR) rec_coop(
    const float* __restrict__ key, const float* __restrict__ values,
    const int*   __restrict__ text, const float* __restrict__ emb,
    const float* __restrict__ Wi1, const float* __restrict__ Wh1,
    const float* __restrict__ bi1, const float* __restrict__ bh1,
    const float* __restrict__ Wi2, const float* __restrict__ Wh2,
    const float* __restrict__ bi2, const float* __restrict__ bh2,
    float* __restrict__ h1buf,  float* __restrict__ h2buf,
    float* __restrict__ ctxbuf, float* __restrict__ ctxp,
    float* __restrict__ states, unsigned* arrive, unsigned* cfl)
{
  const int blk  = blockIdx.x;
  const int tid  = threadIdx.x;
  const int wv   = tid >> 6;
  const int lane = tid & 63;
  const int c    = lane >> 4;   // gate index 0..3 (i,f,g,o)
  const int kq   = lane & 15;   // k-slice within wave
  const int bbase = wv * 4;     // each wave handles 4 batches

  const int d1   = blk;
  const int col1 = c*256 + d1;              // LSTM1 gate column
  const int d2   = blk;                      // valid when blk < 128
  const int col2 = c*128 + d2;              // LSTM2 gate column

  const float badd1 = bi1[col1] + bh1[col1];
  const float badd2 = (blk < 128) ? (bi2[col2] + bh2[col2]) : 0.f;

  __shared__ __align__(16) float h2s[128];
  __shared__ float e_s[128];
  __shared__ float w_s[128];
  __shared__ float pctx[8*128];
  __shared__ float red[32];

  float c1r[4] = {0.f,0.f,0.f,0.f};
  float c2r[4] = {0.f,0.f,0.f,0.f};

  const int cb = blk >> 2, cq3 = blk & 3;
  const int t0 = cq3 * 128;

  for (int t = 0; t < LL; ++t){
    const int p = t & 1;
    const float* h1r  = h1buf + p*(BB*256);
    float*       h1w  = h1buf + (p^1)*(BB*256);
    const float* h2rd = h2buf + p*(BB*128);
    float*       h2w  = h2buf + (p^1)*(BB*128);
    const unsigned ep = (unsigned)(3*t);

    // ===================== Phase A: LSTM1 =====================
    {
      // Stage this step's weight slice into registers (L1-hot: same 10KB every step)
      float w1r[40];
      #pragma unroll
      for (int i = 0; i < 20; ++i){
        #pragma unroll
        for (int j = 0; j < 2; ++j){
          const int k = i*32 + kq*2 + j;
          w1r[i*2+j] = (k < 384) ? Wi1[(size_t)col1*384 + k]
                                 : Wh1[(size_t)col1*256 + (k-384)];
        }
      }
      float h1v0=0.f, h1v1=0.f, h1v2=0.f, h1v3=0.f;
      #pragma unroll
      for (int bi = 0; bi < 4; ++bi){
        const int b = bbase + bi;
        const int row = text[b*LL + t];
        const float* eptr = emb    + (size_t)row*256 + kq*2;
        const float* cptr = ctxbuf + b*128 + kq*2;
        const float* hptr = h1r    + b*256 + kq*2;
        float s = 0.f;
        #pragma unroll
        for (int i = 0; i < 8; ++i){           // k in [0,256): embedding
          float2 v = *(const float2*)(eptr + i*32);
          s = fmaf(w1r[i*2], v.x, s); s = fmaf(w1r[i*2+1], v.y, s);
        }
        #pragma unroll
        for (int i = 8; i < 12; ++i){          // k in [256,384): ctx
          float2 v = *(const float2*)(cptr + (i-8)*32);
          s = fmaf(w1r[i*2], v.x, s); s = fmaf(w1r[i*2+1], v.y, s);
        }
        #pragma unroll
        for (int i = 12; i < 20; ++i){         // k in [384,640): h1
          float2 v = *(const float2*)(hptr + (i-12)*32);
          s = fmaf(w1r[i*2], v.x, s); s = fmaf(w1r[i*2+1], v.y, s);
        }
        s += __shfl_xor(s,1); s += __shfl_xor(s,2);
        s += __shfl_xor(s,4); s += __shfl_xor(s,8);
        const float g  = s + badd1;
        const float gi = __shfl(g, 0),  gf = __shfl(g, 16);
        const float gg = __shfl(g, 32), go = __shfl(g, 48);
        const float cn = sigm(gf)*c1r[bi] + sigm(gi)*tanhf(gg);
        c1r[bi] = cn;
        const float hv = sigm(go)*tanhf(cn);
        if      (bi==0) h1v0 = hv;
        else if (bi==1) h1v1 = hv;
        else if (bi==2) h1v2 = hv;
        else            h1v3 = hv;
      }
      const float hv = (lane==0)?h1v0:((lane==1)?h1v1:((lane==2)?h1v2:h1v3));
      if (lane < 4) h1w[(bbase+lane)*256 + d1] = hv;
    }
    gbar(arrive, blk, tid, ep+1);

    // ===================== Phase B: LSTM2 =====================
    if (blk < 128){
      float w2r[24];
      #pragma unroll
      for (int i = 0; i < 12; ++i){
        #pragma unroll
        for (int j = 0; j < 2; ++j){
          const int k = i*32 + kq*2 + j;
          w2r[i*2+j] = (k < 256) ? Wi2[(size_t)col2*256 + k]
                                 : Wh2[(size_t)col2*128 + (k-256)];
        }
      }
      float h2v0=0.f, h2v1=0.f, h2v2=0.f, h2v3=0.f;
      #pragma unroll
      for (int bi = 0; bi < 4; ++bi){
        const int b = bbase + bi;
        const float* hptr  = h1w  + b*256 + kq*2;  // h1(t)
        const float* h2p   = h2rd + b*128 + kq*2;  // h2(t-1)
        float s = 0.f;
        #pragma unroll
        for (int i = 0; i < 8; ++i){
          float2 v = *(const float2*)(hptr + i*32);
          s = fmaf(w2r[i*2], v.x, s); s = fmaf(w2r[i*2+1], v.y, s);
        }
        #pragma unroll
        for (int i = 8; i < 12; ++i){
          float2 v = *(const float2*)(h2p + (i-8)*32);
          s = fmaf(w2r[i*2], v.x, s); s = fmaf(w2r[i*2+1], v.y, s);
        }
        s += __shfl_xor(s,1); s += __shfl_xor(s,2);
        s += __shfl_xor(s,4); s += __shfl_xor(s,8);
        const float g  = s + badd2;
        const float gi = __shfl(g, 0),  gf = __shfl(g, 16);
        const float gg = __shfl(g, 32), go = __shfl(g, 48);
        const float cn = sigm(gf)*c2r[bi] + sigm(gi)*tanhf(gg);
        c2r[bi] = cn;
        const float hv = sigm(go)*tanhf(cn);
        if      (bi==0) h2v0 = hv;
        else if (bi==1) h2v1 = hv;
        else if (bi==2) h2v2 = hv;
        else            h2v3 = hv;
      }
      const float hv = (lane==0)?h2v0:((lane==1)?h2v1:((lane==2)?h2v2:h2v3));
      if (lane < 4) h2w[(bbase+lane)*128 + d2] = hv;
    }
    gbar(arrive, blk, tid, ep+2);

    // ===================== Phase C: attention =====================
    {
      if (tid < 128) h2s[tid] = h2w[cb*128 + tid];
      __syncthreads();
      // energies for 128 timesteps of this chunk
      {
        const int tl = tid >> 3, k8 = tid & 7;
        const float* kp = key + ((size_t)(cb*TT + t0 + tl))*128 + k8*16;
        float e = 0.f;
        #pragma unroll
        for (int u = 0; u < 4; ++u){
          float4 kv = *(const float4*)(kp + u*4);
          float4 hv = *(const float4*)(h2s + k8*16 + u*4);
          e += kv.x*hv.x + kv.y*hv.y + kv.z*hv.z + kv.w*hv.w;
        }
        e += __shfl_xor(e,1); e += __shfl_xor(e,2); e += __shfl_xor(e,4);
        if (k8 == 0) e_s[tl] = e;
      }
      __syncthreads();
      // local softmax (max-subtracted) over the 128 chunk energies
      float M, S;
      {
        const float v = (tid < 128) ? e_s[tid] : -3.4e38f;
        float mm = v;
        #pragma unroll
        for (int off = 32; off >= 1; off >>= 1) mm = fmaxf(mm, __shfl_xor(mm, off));
        if (lane == 0) red[wv] = mm;
        __syncthreads();
        M = red[0];
        #pragma unroll
        for (int i2 = 1; i2 < 16; ++i2) M = fmaxf(M, red[i2]);
        float w = 0.f;
        if (tid < 128){ w = __expf(v - M); w_s[tid] = w; }
        float ss = w;
        #pragma unroll
        for (int off = 32; off >= 1; off >>= 1) ss += __shfl_xor(ss, off);
        if (lane == 0) red[16+wv] = ss;
        __syncthreads();   // also publishes w_s
        S = 0.f;
        #pragma unroll
        for (int i2 = 0; i2 < 16; ++i2) S += red[16+i2];
      }
      // partial (unnormalized) context for this chunk
      {
        const int v = tid & 127, tc = tid >> 7;
        const float* vp = values + ((size_t)(cb*TT + t0 + tc*16))*128 + v;
        float acc = 0.f;
        #pragma unroll
        for (int j = 0; j < 16; ++j) acc = fmaf(w_s[tc*16+j], vp[(size_t)j*128], acc);
        pctx[tc*128 + v] = acc;
      }
      __syncthreads();
      if (tid < 128){
        float cv = 0.f;
        #pragma unroll
        for (int tc = 0; tc < 8; ++tc) cv += pctx[tc*128 + tid];
        ctxp[(size_t)(cb*4+cq3)*132 + tid] = cv;
        if (tid == 0){
          ctxp[(size_t)(cb*4+cq3)*132 + 128] = M;
          ctxp[(size_t)(cb*4+cq3)*132 + 129] = S;
        }
      }
      __syncthreads();
      if (tid == 0){
        __threadfence();
        __hip_atomic_store(&cfl[cb*4+cq3], (unsigned)(t+1),
                           __ATOMIC_RELEASE, __HIP_MEMORY_SCOPE_AGENT);
      }
      if (cq3 == 0){
        // combine the 4 chunk partials (online-softmax merge)
        int ok;
        do {
          ok = (tid >= 1 && tid < 4)
             ? (__hip_atomic_load(&cfl[cb*4+tid], __ATOMIC_RELAXED,
                                  __HIP_MEMORY_SCOPE_AGENT) >= (unsigned)(t+1))
             : 1;
        } while (__syncthreads_count(ok) < NTHR);
        __threadfence();
        if (tid < 128){
          const float* p0 = ctxp + (size_t)(cb*4+0)*132;
          const float* p1 = ctxp + (size_t)(cb*4+1)*132;
          const float* p2 = ctxp + (size_t)(cb*4+2)*132;
          const float* p3 = ctxp + (size_t)(cb*4+3)*132;
          const float m0=p0[128], s0=p0[129], m1=p1[128], s1=p1[129];
          const float m2=p2[128], s2=p2[129], m3=p3[128], s3=p3[129];
          const float Mm = fmaxf(fmaxf(m0,m1), fmaxf(m2,m3));
          const float a0 = __expf(m0-Mm), a1 = __expf(m1-Mm);
          const float a2 = __expf(m2-Mm), a3 = __expf(m3-Mm);
          const float den = a0*s0 + a1*s1 + a2*s2 + a3*s3;
          const float cv = (a0*p0[tid] + a1*p1[tid] + a2*p2[tid] + a3*p3[tid]) / den;
          ctxbuf[cb*128 + tid] = cv;
          const size_t n = (size_t)cb*LL + t;
          states[n*256 + tid]       = h2s[tid];
          states[n*256 + 128 + tid] = cv;
        }
      }
    }
    gbar(arrive, blk, tid, ep+3);
  }
}

// Final logits GEMM (validated in R1): C[n][v] = states[n][:]·emb[v][:] + b_out[v]
__global__ __launch_bounds__(256) void gemm_kernel(
    const float* __restrict__ A, const float* __restrict__ Bm,
    const float* __restrict__ bias, float* __restrict__ C)
{
  __shared__ float As[16][132];
  __shared__ float Bs[16][132];
  const int tid = threadIdx.x;
  const int tx = tid & 15, ty = tid >> 4;
  const int bn = blockIdx.x, bm = blockIdx.y;

  float acc[8][8];
  #pragma unroll
  for (int i = 0; i < 8; ++i)
    #pragma unroll
    for (int j = 0; j < 8; ++j) acc[i][j] = 0.f;

  const int r  = tid >> 1;
  const int ko = (tid & 1) * 8;
  const float* Ap = A  + ((size_t)(bm*128 + r))*256 + ko;
  const float* Bp = Bm + ((size_t)(bn*128 + r))*256 + ko;

  for (int k0 = 0; k0 < 256; k0 += 16){
    float4 a0 = *(const float4*)(Ap + k0);
    float4 a1 = *(const float4*)(Ap + k0 + 4);
    float4 b0 = *(const float4*)(Bp + k0);
    float4 b1 = *(const float4*)(Bp + k0 + 4);
    As[ko+0][r]=a0.x; As[ko+1][r]=a0.y; As[ko+2][r]=a0.z; As[ko+3][r]=a0.w;
    As[ko+4][r]=a1.x; As[ko+5][r]=a1.y; As[ko+6][r]=a1.z; As[ko+7][r]=a1.w;
    Bs[ko+0][r]=b0.x; Bs[ko+1][r]=b0.y; Bs[ko+2][r]=b0.z; Bs[ko+3][r]=b0.w;
    Bs[ko+4][r]=b1.x; Bs[ko+5][r]=b1.y; Bs[ko+6][r]=b1.z; Bs[ko+7][r]=b1.w;
    __syncthreads();
    #pragma unroll
    for (int k = 0; k < 16; ++k){
      float4 x0 = *(const float4*)&As[k][ty*8];
      float4 x1 = *(const float4*)&As[k][ty*8+4];
      float4 y0 = *(const float4*)&Bs[k][tx*8];
      float4 y1 = *(const float4*)&Bs[k][tx*8+4];
      float av[8] = {x0.x,x0.y,x0.z,x0.w,x1.x,x1.y,x1.z,x1.w};
      float bv[8] = {y0.x,y0.y,y0.z,y0.w,y1.x,y1.y,y1.z,y1.w};
      #pragma unroll
      for (int i = 0; i < 8; ++i)
        #pragma unroll
        for (int j = 0; j < 8; ++j) acc[i][j] += av[i]*bv[j];
    }
    __syncthreads();
  }

  const int c0 = bn*128 + tx*8;
  float bl[8];
  #pragma unroll
  for (int j = 0; j < 8; ++j) bl[j] = bias[c0 + j];
  #pragma unroll
  for (int i = 0; i < 8; ++i){
    size_t row = (size_t)(bm*128 + ty*8 + i);
    float4 o0 = make_float4(acc[i][0]+bl[0], acc[i][1]+bl[1], acc[i][2]+bl[2], acc[i][3]+bl[3]);
    float4 o1 = make_float4(acc[i][4]+bl[4], acc[i][5]+bl[5], acc[i][6]+bl[6], acc[i][7]+bl[7]);
    *(float4*)(C + row*4096 + c0)     = o0;
    *(float4*)(C + row*4096 + c0 + 4) = o1;
  }
}

extern "C" void kernel_launch(void* const* d_in, const int* in_sizes, int n_in,
                              void* d_out, int out_size, void* d_ws, size_t ws_size,
                              hipStream_t stream)
{
  const float* key    = (const float*)d_in[0];
  const float* values = (const float*)d_in[1];
  // d_in[2] = lens (unused by reference path)
  const int*   text   = (const int*)  d_in[3];
  const float* emb    = (const float*)d_in[4];
  const float* Wi1    = (const float*)d_in[5];
  const float* Wh1    = (const float*)d_in[6];
  const float* bi1    = (const float*)d_in[7];
  const float* bh1    = (const float*)d_in[8];
  const float* Wi2    = (const float*)d_in[9];
  const float* Wh2    = (const float*)d_in[10];
  const float* bi2    = (const float*)d_in[11];
  const float* bh2    = (const float*)d_in[12];
  const float* bout   = (const float*)d_in[13];

  // ws layout (floats):
  // states[16384*256] | h1buf[2*64*256] | h2buf[2*64*128] | ctxbuf[64*128]
  // | ctxp[64*4*132] | arrive[256 u32] | cfl[256 u32]
  float* states = (float*)d_ws;
  float* h1buf  = states + (size_t)BB*LL*256;        // 4,194,304
  float* h2buf  = h1buf + 2*BB*256;                  // +32768
  float* ctxbuf = h2buf + 2*BB*128;                  // +16384
  float* ctxp   = ctxbuf + BB*128;                   // +8192
  unsigned* arrive = (unsigned*)(ctxp + BB*4*132);   // +33792
  unsigned* cfl    = arrive + NBLK;

  // zero the recurrent state buffers + flags (ws is poisoned 0xAA each call)
  const size_t zbytes = (size_t)(2*BB*256 + 2*BB*128 + BB*128 + BB*4*132 + 2*NBLK) * 4;
  hipMemsetAsync((void*)h1buf, 0, zbytes, stream);

  void* args[] = { (void*)&key, (void*)&values, (void*)&text, (void*)&emb,
                   (void*)&Wi1, (void*)&Wh1, (void*)&bi1, (void*)&bh1,
                   (void*)&Wi2, (void*)&Wh2, (void*)&bi2, (void*)&bh2,
                   (void*)&h1buf, (void*)&h2buf, (void*)&ctxbuf, (void*)&ctxp,
                   (void*)&states, (void*)&arrive, (void*)&cfl };
  hipLaunchCooperativeKernel((void*)rec_coop, dim3(NBLK), dim3(NTHR), args, 0, stream);

  dim3 grid(VOC/128, (BB*LL)/128);
  gemm_kernel<<<grid, 256, 0, stream>>>(states, emb, bout, (float*)d_out);
}